// Round 1
// baseline (480.576 us; speedup 1.0000x reference)
//
#include <hip/hip_runtime.h>

// SelfAttention: B=4, S=2048, D=1024, fp32 in/out.
// q=x@Wq^T+bq, k=..., v=...; out = softmax(q k^T) @ v   (no 1/sqrt(d) scale)
//
// Strategy: split-bf16 (hi+lo) fp32-emulated MFMA for the precision-critical
// GEMMs (QK projections, q.k^T scores); single bf16 for V and P@V.

#define Bb 4
#define Ss 2048
#define Dd 1024
#define Mtot 8192  // B*S

typedef __bf16 bf16x8 __attribute__((ext_vector_type(8)));
typedef float f32x4 __attribute__((ext_vector_type(4)));
typedef unsigned short u16;
typedef unsigned int u32;
typedef u16 u16x8 __attribute__((ext_vector_type(8)));
typedef u16 u16x4 __attribute__((ext_vector_type(4)));
typedef void __attribute__((address_space(1))) gvoid_t;
typedef void __attribute__((address_space(3))) svoid_t;

__device__ __forceinline__ void gl_lds16(const void* g, void* l) {
  __builtin_amdgcn_global_load_lds((gvoid_t*)g, (svoid_t*)l, 16, 0, 0);
}

__device__ __forceinline__ u16 f2bf(float f) {  // RNE float->bf16
  u32 u = __builtin_bit_cast(u32, f);
  u = (u + 0x7FFFu + ((u >> 16) & 1u)) >> 16;
  return (u16)u;
}
__device__ __forceinline__ float bf2f(u16 h) {
  u32 u = ((u32)h) << 16;
  return __builtin_bit_cast(float, u);
}
__device__ __forceinline__ bf16x8 frag_ld(const char* p) {
  u16x8 v = *(const u16x8*)p;
  return __builtin_bit_cast(bf16x8, v);
}

// stage one 128x32 bf16 tile (8 KB) global -> LDS via global_load_lds width 16.
// LDS layout is linear row-major [128][32] bf16 (64 B per row) as required by
// the wave-uniform-base + lane*16 semantics.
__device__ __forceinline__ void stage8k(const u16* gbase, long row0, int k0, int ld,
                                        char* lds, int tid) {
  const char* gb = (const char*)gbase;
#pragma unroll
  for (int it = 0; it < 2; ++it) {
    int o = it * 4096 + tid * 16;
    int row = o >> 6;
    int colb = o & 63;
    gl_lds16(gb + ((row0 + row) * (long)ld + k0) * 2 + colb, lds + o);
  }
}

// ---------------------------------------------------------------- converts
__global__ void __launch_bounds__(256) split_convert(const float* __restrict__ src,
                                                     u16* __restrict__ hi,
                                                     u16* __restrict__ lo, int n4) {
  int i = blockIdx.x * 256 + threadIdx.x;
  if (i >= n4) return;
  f32x4 v = ((const f32x4*)src)[i];
  u16x4 h, l;
#pragma unroll
  for (int j = 0; j < 4; ++j) {
    u16 hh = f2bf(v[j]);
    h[j] = hh;
    l[j] = f2bf(v[j] - bf2f(hh));
  }
  ((u16x4*)hi)[i] = h;
  ((u16x4*)lo)[i] = l;
}

// ---------------------------------------------------------------- QKV GEMM
// z=0: q (hi/lo out + bq)   z=1: k (hi/lo out + bk)   z=2: v (bf16, transposed)
__global__ void __launch_bounds__(256) qkv_gemm(
    const u16* __restrict__ xhi, const u16* __restrict__ xlo,
    const u16* __restrict__ wqh, const u16* __restrict__ wql,
    const u16* __restrict__ wkh, const u16* __restrict__ wkl,
    const u16* __restrict__ wvh, const u16* __restrict__ wvl,
    const float* __restrict__ bq, const float* __restrict__ bk,
    const float* __restrict__ bv,
    u16* __restrict__ qh, u16* __restrict__ ql,
    u16* __restrict__ kh, u16* __restrict__ kl,
    u16* __restrict__ vt) {
  __shared__ char lds[32768];  // Ahi | Alo | Bhi | Blo (8 KB each)
  const int tid = threadIdx.x;
  const int z = blockIdx.z;
  const u16* wh = (z == 0) ? wqh : (z == 1) ? wkh : wvh;
  const u16* wl = (z == 0) ? wql : (z == 1) ? wkl : wvl;
  const float* bias = (z == 0) ? bq : (z == 1) ? bk : bv;
  const long m0 = (long)blockIdx.y * 128;
  const int n0 = blockIdx.x * 128;

  const int wave = tid >> 6, lane = tid & 63;
  const int wm = wave >> 1, wn = wave & 1;
  const int lr = lane & 15, lk = lane >> 4;

  f32x4 acc[4][4] = {};

  for (int k0 = 0; k0 < Dd; k0 += 32) {
    stage8k(xhi, m0, k0, Dd, lds + 0, tid);
    stage8k(xlo, m0, k0, Dd, lds + 8192, tid);
    stage8k(wh, n0, k0, Dd, lds + 16384, tid);
    stage8k(wl, n0, k0, Dd, lds + 24576, tid);
    __syncthreads();
    bf16x8 ah[4], al[4], bh[4], bl[4];
#pragma unroll
    for (int i = 0; i < 4; ++i) {
      int ra = (wm * 64 + i * 16 + lr) * 64 + lk * 16;
      int rb = (wn * 64 + i * 16 + lr) * 64 + lk * 16;
      ah[i] = frag_ld(lds + ra);
      al[i] = frag_ld(lds + 8192 + ra);
      bh[i] = frag_ld(lds + 16384 + rb);
      bl[i] = frag_ld(lds + 24576 + rb);
    }
#pragma unroll
    for (int mt = 0; mt < 4; ++mt)
#pragma unroll
      for (int nt = 0; nt < 4; ++nt) {
        acc[mt][nt] = __builtin_amdgcn_mfma_f32_16x16x32_bf16(ah[mt], bh[nt], acc[mt][nt], 0, 0, 0);
        acc[mt][nt] = __builtin_amdgcn_mfma_f32_16x16x32_bf16(ah[mt], bl[nt], acc[mt][nt], 0, 0, 0);
        acc[mt][nt] = __builtin_amdgcn_mfma_f32_16x16x32_bf16(al[mt], bh[nt], acc[mt][nt], 0, 0, 0);
      }
    __syncthreads();
  }

#pragma unroll
  for (int mt = 0; mt < 4; ++mt)
#pragma unroll
    for (int nt = 0; nt < 4; ++nt)
#pragma unroll
      for (int r = 0; r < 4; ++r) {
        long gm = m0 + wm * 64 + mt * 16 + lk * 4 + r;
        int e = n0 + wn * 64 + nt * 16 + lr;
        float v = acc[mt][nt][r] + bias[e];
        if (z == 2) {
          long b = gm >> 11, s = gm & 2047;
          vt[(b * Dd + e) * (long)Ss + s] = f2bf(v);
        } else {
          u16 hi = f2bf(v);
          float lo = v - bf2f(hi);
          u16* oh = (z == 0) ? qh : kh;
          u16* ol = (z == 0) ? ql : kl;
          oh[gm * Dd + e] = hi;
          ol[gm * Dd + e] = f2bf(lo);
        }
      }
}

// ---------------------------------------------------------------- scores GEMM
// scores[b][i][j] = q[b,i,:] . k[b,j,:]   (split x split, fp32 out)
__global__ void __launch_bounds__(256) score_gemm(
    const u16* __restrict__ qh, const u16* __restrict__ ql,
    const u16* __restrict__ kh, const u16* __restrict__ kl,
    float* __restrict__ scores) {
  __shared__ char lds[32768];
  const int tid = threadIdx.x;
  const int z = blockIdx.z;  // batch
  const long abase = (long)z * Ss * Dd;
  const long m0 = (long)blockIdx.y * 128;
  const int n0 = blockIdx.x * 128;

  const int wave = tid >> 6, lane = tid & 63;
  const int wm = wave >> 1, wn = wave & 1;
  const int lr = lane & 15, lk = lane >> 4;

  f32x4 acc[4][4] = {};

  for (int k0 = 0; k0 < Dd; k0 += 32) {
    stage8k(qh + abase, m0, k0, Dd, lds + 0, tid);
    stage8k(ql + abase, m0, k0, Dd, lds + 8192, tid);
    stage8k(kh + abase, n0, k0, Dd, lds + 16384, tid);
    stage8k(kl + abase, n0, k0, Dd, lds + 24576, tid);
    __syncthreads();
    bf16x8 ah[4], al[4], bh[4], bl[4];
#pragma unroll
    for (int i = 0; i < 4; ++i) {
      int ra = (wm * 64 + i * 16 + lr) * 64 + lk * 16;
      int rb = (wn * 64 + i * 16 + lr) * 64 + lk * 16;
      ah[i] = frag_ld(lds + ra);
      al[i] = frag_ld(lds + 8192 + ra);
      bh[i] = frag_ld(lds + 16384 + rb);
      bl[i] = frag_ld(lds + 24576 + rb);
    }
#pragma unroll
    for (int mt = 0; mt < 4; ++mt)
#pragma unroll
      for (int nt = 0; nt < 4; ++nt) {
        acc[mt][nt] = __builtin_amdgcn_mfma_f32_16x16x32_bf16(ah[mt], bh[nt], acc[mt][nt], 0, 0, 0);
        acc[mt][nt] = __builtin_amdgcn_mfma_f32_16x16x32_bf16(ah[mt], bl[nt], acc[mt][nt], 0, 0, 0);
        acc[mt][nt] = __builtin_amdgcn_mfma_f32_16x16x32_bf16(al[mt], bh[nt], acc[mt][nt], 0, 0, 0);
      }
    __syncthreads();
  }

  float* srow = scores + (long)z * Ss * Ss;
#pragma unroll
  for (int mt = 0; mt < 4; ++mt)
#pragma unroll
    for (int nt = 0; nt < 4; ++nt)
#pragma unroll
      for (int r = 0; r < 4; ++r) {
        long i = m0 + wm * 64 + mt * 16 + lk * 4 + r;
        int j = n0 + wn * 64 + nt * 16 + lr;
        srow[i * Ss + j] = acc[mt][nt][r];
      }
}

// ---------------------------------------------------------------- softmax
// one block per row; reads 2048 fp32, writes 2048 bf16 P aliased over the
// row's first half (all reads complete before first barrier).
__global__ void __launch_bounds__(256) softmax_rows(float* __restrict__ scores) {
  const long r = blockIdx.x;
  float* row = scores + r * Ss;
  const int t = threadIdx.x;
  const int wave = t >> 6, lane = t & 63;
  f32x4 v0 = ((const f32x4*)row)[t * 2];
  f32x4 v1 = ((const f32x4*)row)[t * 2 + 1];
  float a[8];
#pragma unroll
  for (int j = 0; j < 4; ++j) { a[j] = v0[j]; a[4 + j] = v1[j]; }

  float m = a[0];
#pragma unroll
  for (int j = 1; j < 8; ++j) m = fmaxf(m, a[j]);
#pragma unroll
  for (int off = 32; off >= 1; off >>= 1) m = fmaxf(m, __shfl_xor(m, off));
  __shared__ float red[4];
  if (lane == 0) red[wave] = m;
  __syncthreads();
  m = fmaxf(fmaxf(red[0], red[1]), fmaxf(red[2], red[3]));

  float e[8];
  float s = 0.f;
#pragma unroll
  for (int j = 0; j < 8; ++j) { e[j] = __expf(a[j] - m); s += e[j]; }
#pragma unroll
  for (int off = 32; off >= 1; off >>= 1) s += __shfl_xor(s, off);
  __syncthreads();
  if (lane == 0) red[wave] = s;
  __syncthreads();
  s = red[0] + red[1] + red[2] + red[3];
  float inv = 1.0f / s;

  u16x8 pk;
#pragma unroll
  for (int j = 0; j < 8; ++j) pk[j] = f2bf(e[j] * inv);
  ((u16x8*)row)[t] = pk;  // bf16 P over first half of the fp32 row
}

// ---------------------------------------------------------------- PV GEMM
// out[b][i][e] = sum_j P[b][i][j] * vt[b][e][j]   (single bf16)
__global__ void __launch_bounds__(256) pv_gemm(const u16* __restrict__ P,
                                               const u16* __restrict__ vt,
                                               float* __restrict__ out) {
  __shared__ char lds[16384];  // A | B
  const int tid = threadIdx.x;
  const int z = blockIdx.z;  // batch
  const u16* A = P + (long)z * Ss * 4096;    // P rows aliased in fp32 rows: stride 4096 u16
  const u16* Bp = vt + (long)z * Dd * Ss;    // [1024][2048]
  const long m0 = (long)blockIdx.y * 128;
  const int n0 = blockIdx.x * 128;

  const int wave = tid >> 6, lane = tid & 63;
  const int wm = wave >> 1, wn = wave & 1;
  const int lr = lane & 15, lk = lane >> 4;

  f32x4 acc[4][4] = {};

  for (int k0 = 0; k0 < Ss; k0 += 32) {
    stage8k(A, m0, k0, 4096, lds + 0, tid);
    stage8k(Bp, n0, k0, Ss, lds + 8192, tid);
    __syncthreads();
    bf16x8 af[4], bf[4];
#pragma unroll
    for (int i = 0; i < 4; ++i) {
      int ra = (wm * 64 + i * 16 + lr) * 64 + lk * 16;
      int rb = (wn * 64 + i * 16 + lr) * 64 + lk * 16;
      af[i] = frag_ld(lds + ra);
      bf[i] = frag_ld(lds + 8192 + rb);
    }
#pragma unroll
    for (int mt = 0; mt < 4; ++mt)
#pragma unroll
      for (int nt = 0; nt < 4; ++nt)
        acc[mt][nt] = __builtin_amdgcn_mfma_f32_16x16x32_bf16(af[mt], bf[nt], acc[mt][nt], 0, 0, 0);
    __syncthreads();
  }

  float* orow = out + (long)z * Ss * Dd;
#pragma unroll
  for (int mt = 0; mt < 4; ++mt)
#pragma unroll
    for (int nt = 0; nt < 4; ++nt)
#pragma unroll
      for (int r = 0; r < 4; ++r) {
        long i = m0 + wm * 64 + mt * 16 + lk * 4 + r;
        int e = n0 + wn * 64 + nt * 16 + lr;
        orow[i * Dd + e] = acc[mt][nt][r];
      }
}

// ---------------------------------------------------------------- launch
extern "C" void kernel_launch(void* const* d_in, const int* in_sizes, int n_in,
                              void* d_out, int out_size, void* d_ws, size_t ws_size,
                              hipStream_t stream) {
  const float* x = (const float*)d_in[0];
  const float* Wq = (const float*)d_in[1];
  const float* bq = (const float*)d_in[2];
  const float* Wk = (const float*)d_in[3];
  const float* bk = (const float*)d_in[4];
  const float* Wv = (const float*)d_in[5];
  const float* bv = (const float*)d_in[6];
  float* out = (float*)d_out;

  // workspace carve (~164 MB total)
  char* p = (char*)d_ws;
  float* scores = (float*)p;              // 67,108,864 B (later: P bf16 aliased)
  u16* xhi = (u16*)p;                     // aliased under scores region,
  u16* xlo = (u16*)(p + 16777216);        // dead before scores are written
  p += 67108864;
  u16* qh = (u16*)p; p += 16777216;
  u16* ql = (u16*)p; p += 16777216;
  u16* kh = (u16*)p; p += 16777216;
  u16* kl = (u16*)p; p += 16777216;
  u16* vt = (u16*)p; p += 16777216;
  u16* wqh = (u16*)p; p += 2097152;
  u16* wql = (u16*)p; p += 2097152;
  u16* wkh = (u16*)p; p += 2097152;
  u16* wkl = (u16*)p; p += 2097152;
  u16* wvh = (u16*)p; p += 2097152;
  u16* wvl = (u16*)p; p += 2097152;

  // 1. split converts
  split_convert<<<dim3(8192), dim3(256), 0, stream>>>(x, xhi, xlo, (Mtot * Dd) / 4);
  split_convert<<<dim3(1024), dim3(256), 0, stream>>>(Wq, wqh, wql, (Dd * Dd) / 4);
  split_convert<<<dim3(1024), dim3(256), 0, stream>>>(Wk, wkh, wkl, (Dd * Dd) / 4);
  split_convert<<<dim3(1024), dim3(256), 0, stream>>>(Wv, wvh, wvl, (Dd * Dd) / 4);

  // 2. QKV projection
  qkv_gemm<<<dim3(Dd / 128, Mtot / 128, 3), dim3(256), 0, stream>>>(
      xhi, xlo, wqh, wql, wkh, wkl, wvh, wvl, bq, bk, bv, qh, ql, kh, kl, vt);

  // 3. scores = q k^T
  score_gemm<<<dim3(Ss / 128, Ss / 128, Bb), dim3(256), 0, stream>>>(qh, ql, kh, kl, scores);

  // 4. softmax rows (P bf16 written in place)
  softmax_rows<<<dim3(Bb * Ss), dim3(256), 0, stream>>>(scores);

  // 5. out = P @ v
  pv_gemm<<<dim3(Dd / 128, Ss / 128, Bb), dim3(256), 0, stream>>>((const u16*)scores, vt, out);
}

// Round 2
// 437.557 us; speedup vs baseline: 1.0983x; 1.0983x over previous
//
#include <hip/hip_runtime.h>

// SelfAttention: B=4, S=2048, D=1024, fp32 in/out.
// q=x@Wq^T+bq, k=..., v=...; out = softmax(q k^T) @ v   (no 1/sqrt(d) scale)
//
// Precision plan: split-bf16 (hi+lo) 3-term fp32-emulated MFMA for q/k
// projections and q.k^T scores (score abs error ~1e-4). Single bf16 MFMA for
// the v projection (dv ~1.5e-3, harmless through softmax averaging); f16 for
// P and v in the PV GEMM (error ~3e-4).

#define Bb 4
#define Ss 2048
#define Dd 1024
#define Mtot 8192  // B*S

typedef __bf16 bf16x8 __attribute__((ext_vector_type(8)));
typedef _Float16 f16x8 __attribute__((ext_vector_type(8)));
typedef float f32x4 __attribute__((ext_vector_type(4)));
typedef unsigned short u16;
typedef unsigned int u32;
typedef u16 u16x8 __attribute__((ext_vector_type(8)));
typedef u16 u16x4 __attribute__((ext_vector_type(4)));
typedef void __attribute__((address_space(1))) gvoid_t;
typedef void __attribute__((address_space(3))) svoid_t;

__device__ __forceinline__ void gl_lds16(const void* g, void* l) {
  __builtin_amdgcn_global_load_lds((gvoid_t*)g, (svoid_t*)l, 16, 0, 0);
}

__device__ __forceinline__ u16 f2bf(float f) {  // RNE float->bf16
  u32 u = __builtin_bit_cast(u32, f);
  u = (u + 0x7FFFu + ((u >> 16) & 1u)) >> 16;
  return (u16)u;
}
__device__ __forceinline__ float bf2f(u16 h) {
  u32 u = ((u32)h) << 16;
  return __builtin_bit_cast(float, u);
}
__device__ __forceinline__ u16 f2h(float f) {  // RNE float->f16 bits
  return __builtin_bit_cast(u16, (_Float16)f);
}
__device__ __forceinline__ bf16x8 frag_ld(const char* p) {
  u16x8 v = *(const u16x8*)p;
  return __builtin_bit_cast(bf16x8, v);
}
__device__ __forceinline__ f16x8 frag_ld_h(const char* p) {
  u16x8 v = *(const u16x8*)p;
  return __builtin_bit_cast(f16x8, v);
}

// stage one 128x32 bf16 tile (8 KB) global -> LDS via global_load_lds width 16.
// LDS layout is linear row-major [128][32] u16 (64 B per row) as required by
// the wave-uniform-base + lane*16 semantics.
__device__ __forceinline__ void stage8k(const u16* gbase, long row0, int k0, int ld,
                                        char* lds, int tid) {
  const char* gb = (const char*)gbase;
#pragma unroll
  for (int it = 0; it < 2; ++it) {
    int o = it * 4096 + tid * 16;
    int row = o >> 6;
    int colb = o & 63;
    gl_lds16(gb + ((row0 + row) * (long)ld + k0) * 2 + colb, lds + o);
  }
}

// ---------------------------------------------------------------- converts
// blocks [0,8192): x   [8192,9216): Wq   [9216,10240): Wk   [10240,11264): Wv
__global__ void __launch_bounds__(256) split_convert_all(
    const float* __restrict__ x, const float* __restrict__ Wq,
    const float* __restrict__ Wk, const float* __restrict__ Wv,
    u16* __restrict__ xhi, u16* __restrict__ xlo,
    u16* __restrict__ wqh, u16* __restrict__ wql,
    u16* __restrict__ wkh, u16* __restrict__ wkl,
    u16* __restrict__ wvh, u16* __restrict__ wvl) {
  long b = blockIdx.x;
  const float* src;
  u16 *hi, *lo;
  long i;
  if (b < 8192) {
    src = x; hi = xhi; lo = xlo;
    i = b * 256 + threadIdx.x;
  } else {
    int w = (int)((b - 8192) >> 10);
    src = (w == 0) ? Wq : (w == 1) ? Wk : Wv;
    hi = (w == 0) ? wqh : (w == 1) ? wkh : wvh;
    lo = (w == 0) ? wql : (w == 1) ? wkl : wvl;
    i = ((b - 8192) & 1023) * 256 + threadIdx.x;
  }
  f32x4 v = ((const f32x4*)src)[i];
  u16x4 h, l;
#pragma unroll
  for (int j = 0; j < 4; ++j) {
    u16 hh = f2bf(v[j]);
    h[j] = hh;
    l[j] = f2bf(v[j] - bf2f(hh));
  }
  ((u16x4*)hi)[i] = h;
  ((u16x4*)lo)[i] = l;
}

// ---------------------------------------------------------------- QKV GEMM
// z=0: q (hi/lo bf16 out + bq)  z=1: k (hi/lo bf16 out + bk)
// z=2: v (single-MFMA path, f16 out, transposed)
__global__ void __launch_bounds__(256) qkv_gemm(
    const u16* __restrict__ xhi, const u16* __restrict__ xlo,
    const u16* __restrict__ wqh, const u16* __restrict__ wql,
    const u16* __restrict__ wkh, const u16* __restrict__ wkl,
    const u16* __restrict__ wvh,
    const float* __restrict__ bq, const float* __restrict__ bk,
    const float* __restrict__ bv,
    u16* __restrict__ qh, u16* __restrict__ ql,
    u16* __restrict__ kh, u16* __restrict__ kl,
    u16* __restrict__ vt) {
  __shared__ char lds[32768];  // Ahi | Alo | Bhi | Blo (8 KB each)
  const int tid = threadIdx.x;
  const int z = blockIdx.z;
  const u16* wh = (z == 0) ? wqh : (z == 1) ? wkh : wvh;
  const u16* wl = (z == 0) ? wql : wkl;  // unused for z==2
  const float* bias = (z == 0) ? bq : (z == 1) ? bk : bv;
  const long m0 = (long)blockIdx.y * 128;
  const int n0 = blockIdx.x * 128;

  const int wave = tid >> 6, lane = tid & 63;
  const int wm = wave >> 1, wn = wave & 1;
  const int lr = lane & 15, lk = lane >> 4;

  f32x4 acc[4][4] = {};

  for (int k0 = 0; k0 < Dd; k0 += 32) {
    stage8k(xhi, m0, k0, Dd, lds + 0, tid);
    stage8k(wh, n0, k0, Dd, lds + 16384, tid);
    if (z < 2) {
      stage8k(xlo, m0, k0, Dd, lds + 8192, tid);
      stage8k(wl, n0, k0, Dd, lds + 24576, tid);
    }
    __syncthreads();
    bf16x8 ah[4], al[4], bh[4], bl[4];
#pragma unroll
    for (int i = 0; i < 4; ++i) {
      int ra = (wm * 64 + i * 16 + lr) * 64 + lk * 16;
      int rb = (wn * 64 + i * 16 + lr) * 64 + lk * 16;
      ah[i] = frag_ld(lds + ra);
      bh[i] = frag_ld(lds + 16384 + rb);
      if (z < 2) {
        al[i] = frag_ld(lds + 8192 + ra);
        bl[i] = frag_ld(lds + 24576 + rb);
      }
    }
#pragma unroll
    for (int mt = 0; mt < 4; ++mt)
#pragma unroll
      for (int nt = 0; nt < 4; ++nt) {
        acc[mt][nt] = __builtin_amdgcn_mfma_f32_16x16x32_bf16(ah[mt], bh[nt], acc[mt][nt], 0, 0, 0);
        if (z < 2) {
          acc[mt][nt] = __builtin_amdgcn_mfma_f32_16x16x32_bf16(ah[mt], bl[nt], acc[mt][nt], 0, 0, 0);
          acc[mt][nt] = __builtin_amdgcn_mfma_f32_16x16x32_bf16(al[mt], bh[nt], acc[mt][nt], 0, 0, 0);
        }
      }
    __syncthreads();
  }

#pragma unroll
  for (int mt = 0; mt < 4; ++mt)
#pragma unroll
    for (int nt = 0; nt < 4; ++nt)
#pragma unroll
      for (int r = 0; r < 4; ++r) {
        long gm = m0 + wm * 64 + mt * 16 + lk * 4 + r;
        int e = n0 + wn * 64 + nt * 16 + lr;
        float v = acc[mt][nt][r] + bias[e];
        if (z == 2) {
          long b = gm >> 11, s = gm & 2047;
          vt[(b * Dd + e) * (long)Ss + s] = f2h(v);
        } else {
          u16 hi = f2bf(v);
          float lo = v - bf2f(hi);
          u16* oh = (z == 0) ? qh : kh;
          u16* ol = (z == 0) ? ql : kl;
          oh[gm * Dd + e] = hi;
          ol[gm * Dd + e] = f2bf(lo);
        }
      }
}

// ---------------------------------------------------------------- scores GEMM
// scores[b][i][j] = q[b,i,:] . k[b,j,:]   (split x split, fp32 out)
__global__ void __launch_bounds__(256) score_gemm(
    const u16* __restrict__ qh, const u16* __restrict__ ql,
    const u16* __restrict__ kh, const u16* __restrict__ kl,
    float* __restrict__ scores) {
  __shared__ char lds[32768];
  const int tid = threadIdx.x;
  const int z = blockIdx.z;  // batch
  const long abase = (long)z * Ss * Dd;
  const long m0 = (long)blockIdx.y * 128;
  const int n0 = blockIdx.x * 128;

  const int wave = tid >> 6, lane = tid & 63;
  const int wm = wave >> 1, wn = wave & 1;
  const int lr = lane & 15, lk = lane >> 4;

  f32x4 acc[4][4] = {};

  for (int k0 = 0; k0 < Dd; k0 += 32) {
    stage8k(qh + abase, m0, k0, Dd, lds + 0, tid);
    stage8k(ql + abase, m0, k0, Dd, lds + 8192, tid);
    stage8k(kh + abase, n0, k0, Dd, lds + 16384, tid);
    stage8k(kl + abase, n0, k0, Dd, lds + 24576, tid);
    __syncthreads();
    bf16x8 ah[4], al[4], bh[4], bl[4];
#pragma unroll
    for (int i = 0; i < 4; ++i) {
      int ra = (wm * 64 + i * 16 + lr) * 64 + lk * 16;
      int rb = (wn * 64 + i * 16 + lr) * 64 + lk * 16;
      ah[i] = frag_ld(lds + ra);
      al[i] = frag_ld(lds + 8192 + ra);
      bh[i] = frag_ld(lds + 16384 + rb);
      bl[i] = frag_ld(lds + 24576 + rb);
    }
#pragma unroll
    for (int mt = 0; mt < 4; ++mt)
#pragma unroll
      for (int nt = 0; nt < 4; ++nt) {
        acc[mt][nt] = __builtin_amdgcn_mfma_f32_16x16x32_bf16(ah[mt], bh[nt], acc[mt][nt], 0, 0, 0);
        acc[mt][nt] = __builtin_amdgcn_mfma_f32_16x16x32_bf16(ah[mt], bl[nt], acc[mt][nt], 0, 0, 0);
        acc[mt][nt] = __builtin_amdgcn_mfma_f32_16x16x32_bf16(al[mt], bh[nt], acc[mt][nt], 0, 0, 0);
      }
    __syncthreads();
  }

  float* srow = scores + (long)z * Ss * Ss;
#pragma unroll
  for (int mt = 0; mt < 4; ++mt)
#pragma unroll
    for (int nt = 0; nt < 4; ++nt)
#pragma unroll
      for (int r = 0; r < 4; ++r) {
        long i = m0 + wm * 64 + mt * 16 + lk * 4 + r;
        int j = n0 + wn * 64 + nt * 16 + lr;
        srow[i * Ss + j] = acc[mt][nt][r];
      }
}

// ---------------------------------------------------------------- softmax
// one block per row; reads 2048 fp32, writes 2048 f16 P aliased over the
// row's first half (all reads complete before first barrier).
__global__ void __launch_bounds__(256) softmax_rows(float* __restrict__ scores) {
  const long r = blockIdx.x;
  float* row = scores + r * Ss;
  const int t = threadIdx.x;
  const int wave = t >> 6, lane = t & 63;
  f32x4 v0 = ((const f32x4*)row)[t * 2];
  f32x4 v1 = ((const f32x4*)row)[t * 2 + 1];
  float a[8];
#pragma unroll
  for (int j = 0; j < 4; ++j) { a[j] = v0[j]; a[4 + j] = v1[j]; }

  float m = a[0];
#pragma unroll
  for (int j = 1; j < 8; ++j) m = fmaxf(m, a[j]);
#pragma unroll
  for (int off = 32; off >= 1; off >>= 1) m = fmaxf(m, __shfl_xor(m, off));
  __shared__ float red[4];
  if (lane == 0) red[wave] = m;
  __syncthreads();
  m = fmaxf(fmaxf(red[0], red[1]), fmaxf(red[2], red[3]));

  float e[8];
  float s = 0.f;
#pragma unroll
  for (int j = 0; j < 8; ++j) { e[j] = __expf(a[j] - m); s += e[j]; }
#pragma unroll
  for (int off = 32; off >= 1; off >>= 1) s += __shfl_xor(s, off);
  __syncthreads();
  if (lane == 0) red[wave] = s;
  __syncthreads();
  s = red[0] + red[1] + red[2] + red[3];
  float inv = 1.0f / s;

  u16x8 pk;
#pragma unroll
  for (int j = 0; j < 8; ++j) pk[j] = f2h(e[j] * inv);
  ((u16x8*)row)[t] = pk;  // f16 P over first half of the fp32 row
}

// ---------------------------------------------------------------- PV GEMM
// out[b][i][e] = sum_j P[b][i][j] * vt[b][e][j]   (f16)
__global__ void __launch_bounds__(256) pv_gemm(const u16* __restrict__ P,
                                               const u16* __restrict__ vt,
                                               float* __restrict__ out) {
  __shared__ char lds[16384];  // A | B
  const int tid = threadIdx.x;
  const int z = blockIdx.z;  // batch
  const u16* A = P + (long)z * Ss * 4096;    // P rows aliased in fp32 rows: stride 4096 u16
  const u16* Bp = vt + (long)z * Dd * Ss;    // [1024][2048]
  const long m0 = (long)blockIdx.y * 128;
  const int n0 = blockIdx.x * 128;

  const int wave = tid >> 6, lane = tid & 63;
  const int wm = wave >> 1, wn = wave & 1;
  const int lr = lane & 15, lk = lane >> 4;

  f32x4 acc[4][4] = {};

  for (int k0 = 0; k0 < Ss; k0 += 32) {
    stage8k(A, m0, k0, 4096, lds + 0, tid);
    stage8k(Bp, n0, k0, Ss, lds + 8192, tid);
    __syncthreads();
    f16x8 af[4], bf[4];
#pragma unroll
    for (int i = 0; i < 4; ++i) {
      int ra = (wm * 64 + i * 16 + lr) * 64 + lk * 16;
      int rb = (wn * 64 + i * 16 + lr) * 64 + lk * 16;
      af[i] = frag_ld_h(lds + ra);
      bf[i] = frag_ld_h(lds + 8192 + rb);
    }
#pragma unroll
    for (int mt = 0; mt < 4; ++mt)
#pragma unroll
      for (int nt = 0; nt < 4; ++nt)
        acc[mt][nt] = __builtin_amdgcn_mfma_f32_16x16x32_f16(af[mt], bf[nt], acc[mt][nt], 0, 0, 0);
    __syncthreads();
  }

  float* orow = out + (long)z * Ss * Dd;
#pragma unroll
  for (int mt = 0; mt < 4; ++mt)
#pragma unroll
    for (int nt = 0; nt < 4; ++nt)
#pragma unroll
      for (int r = 0; r < 4; ++r) {
        long i = m0 + wm * 64 + mt * 16 + lk * 4 + r;
        int e = n0 + wn * 64 + nt * 16 + lr;
        orow[i * Dd + e] = acc[mt][nt][r];
      }
}

// ---------------------------------------------------------------- launch
extern "C" void kernel_launch(void* const* d_in, const int* in_sizes, int n_in,
                              void* d_out, int out_size, void* d_ws, size_t ws_size,
                              hipStream_t stream) {
  const float* x = (const float*)d_in[0];
  const float* Wq = (const float*)d_in[1];
  const float* bq = (const float*)d_in[2];
  const float* Wk = (const float*)d_in[3];
  const float* bk = (const float*)d_in[4];
  const float* Wv = (const float*)d_in[5];
  const float* bv = (const float*)d_in[6];
  float* out = (float*)d_out;

  // workspace carve (~164 MB total)
  char* p = (char*)d_ws;
  float* scores = (float*)p;              // 67,108,864 B (later: P f16 aliased)
  u16* xhi = (u16*)p;                     // aliased under scores region,
  u16* xlo = (u16*)(p + 16777216);        // dead before scores are written
  p += 67108864;
  u16* qh = (u16*)p; p += 16777216;
  u16* ql = (u16*)p; p += 16777216;
  u16* kh = (u16*)p; p += 16777216;
  u16* kl = (u16*)p; p += 16777216;
  u16* vt = (u16*)p; p += 16777216;
  u16* wqh = (u16*)p; p += 2097152;
  u16* wql = (u16*)p; p += 2097152;
  u16* wkh = (u16*)p; p += 2097152;
  u16* wkl = (u16*)p; p += 2097152;
  u16* wvh = (u16*)p; p += 2097152;
  u16* wvl = (u16*)p; p += 2097152;

  // 1. split converts (x + 3 weights in one launch)
  split_convert_all<<<dim3(11264), dim3(256), 0, stream>>>(
      x, Wq, Wk, Wv, xhi, xlo, wqh, wql, wkh, wkl, wvh, wvl);

  // 2. QKV projection
  qkv_gemm<<<dim3(Dd / 128, Mtot / 128, 3), dim3(256), 0, stream>>>(
      xhi, xlo, wqh, wql, wkh, wkl, wvh, bq, bk, bv, qh, ql, kh, kl, vt);

  // 3. scores = q k^T
  score_gemm<<<dim3(Ss / 128, Ss / 128, Bb), dim3(256), 0, stream>>>(qh, ql, kh, kl, scores);

  // 4. softmax rows (P f16 written in place)
  softmax_rows<<<dim3(Bb * Ss), dim3(256), 0, stream>>>(scores);

  // 5. out = P @ v
  pv_gemm<<<dim3(Dd / 128, Ss / 128, Bb), dim3(256), 0, stream>>>((const u16*)scores, vt, out);
}